// Round 5
// baseline (422.472 us; speedup 1.0000x reference)
//
#include <hip/hip_runtime.h>
#include <hip/hip_bf16.h>

#define DIN 300
#define KP  320            // K padded to multiple of 32 for MFMA
#define NH  64
#define CHUNK 2048         // k_pred: columns per block
#define NT (CHUNK / 128)   // 16 tiles per block

typedef __bf16 bf16x8 __attribute__((ext_vector_type(8)));
typedef float  f32x4  __attribute__((ext_vector_type(4)));

__device__ inline float wave_sum(float v){
#pragma unroll
  for (int m = 32; m >= 1; m >>= 1) v += __shfl_xor(v, m, 64);
  return v;
}

// ---------- convert X -> bf16 padded [N][KP] ----------
__global__ __launch_bounds__(256) void k_cvtX(const float* __restrict__ X,
                                              __hip_bfloat16* __restrict__ Xb){
  int row = blockIdx.x;
  const float* xr = X + (size_t)row * DIN;
  __hip_bfloat16* o = Xb + (size_t)row * KP;
  for (int k = threadIdx.x; k < KP; k += 256)
    o[k] = __float2bfloat16(k < DIN ? xr[k] : 0.f);
}

// ---------- build transposed weight [256][KP] bf16: cols = [Wt_pos|Wb_pos|Wt_neg|Wb_neg] ----------
__global__ __launch_bounds__(256) void k_cvtW(const float* __restrict__ Wpb,
                                              const float* __restrict__ Wnb,
                                              __hip_bfloat16* __restrict__ Wtb){
  int c = blockIdx.x;                 // 0..255
  int sel = c >> 6, jj = c & 63;
  const float* W = (sel < 2 ? Wpb : Wnb) + (size_t)(sel & 1) * DIN * NH + jj;
  __hip_bfloat16* o = Wtb + (size_t)c * KP;
  for (int k = threadIdx.x; k < KP; k += 256)
    o[k] = __float2bfloat16(k < DIN ? W[(size_t)k * NH] : 0.f);
}

// ---------- XW[N][256] = Xb @ Wcat  (MFMA bf16) ----------
__global__ __launch_bounds__(256) void k_gemm_base(const __hip_bfloat16* __restrict__ Xb,
                                                   const __hip_bfloat16* __restrict__ Wtb,
                                                   float* __restrict__ XW){
  const int wave = threadIdx.x >> 6, lane = threadIdx.x & 63;
  const int ti = blockIdx.y * 64 + wave * 16;     // row tile (16 rows/wave)
  const int cj = blockIdx.x * 64;                 // col tile
  const int r0 = lane & 15, kq = (lane >> 4) * 8;
  const unsigned short* Xp = (const unsigned short*)Xb;
  const unsigned short* Wp = (const unsigned short*)Wtb;
  f32x4 acc[4] = {};
  for (int ks = 0; ks < KP / 32; ++ks){
    int kb = ks * 32 + kq;
    bf16x8 a = *(const bf16x8*)(Xp + (size_t)(ti + r0) * KP + kb);
#pragma unroll
    for (int js = 0; js < 4; ++js){
      bf16x8 b = *(const bf16x8*)(Wp + (size_t)(cj + js * 16 + r0) * KP + kb);
      acc[js] = __builtin_amdgcn_mfma_f32_16x16x32_bf16(a, b, acc[js], 0, 0, 0);
    }
  }
  const int orow = ti + (lane >> 4) * 4;
  const int oc = cj + (lane & 15);
#pragma unroll
  for (int js = 0; js < 4; ++js)
#pragma unroll
    for (int i = 0; i < 4; ++i)
      XW[(size_t)(orow + i) * 256 + oc + js * 16] = acc[js][i];
}

// ---------- CSR build ----------
__global__ void k_hist(const int* __restrict__ pr, const int* __restrict__ nr,
                       int* __restrict__ cp, int* __restrict__ cn, int E){
  int i = blockIdx.x * 256 + threadIdx.x;
  if (i < E){ atomicAdd(cp + pr[i], 1); atomicAdd(cn + nr[i], 1); }
}

__global__ __launch_bounds__(1024) void k_scan(const int* __restrict__ c0, int* __restrict__ o0,
                                               const int* __restrict__ c1, int* __restrict__ o1, int n){
  const int* cnt = blockIdx.x ? c1 : c0;
  int* off = blockIdx.x ? o1 : o0;
  __shared__ int lds[1024];
  int t = threadIdx.x;
  int ept = n >> 10;
  int s = 0;
  for (int i = 0; i < ept; ++i) s += cnt[t * ept + i];
  lds[t] = s; __syncthreads();
  for (int d = 1; d < 1024; d <<= 1){
    int add = (t >= d) ? lds[t - d] : 0;
    __syncthreads();
    lds[t] += add;
    __syncthreads();
  }
  int base = t ? lds[t - 1] : 0;
  for (int i = 0; i < ept; ++i){ off[t * ept + i] = base; base += cnt[t * ept + i]; }
}

__global__ void k_fill(const int* __restrict__ pr, const int* __restrict__ pc,
                       const int* __restrict__ nr, const int* __restrict__ nc,
                       const int* __restrict__ op, const int* __restrict__ on,
                       int* __restrict__ curp, int* __restrict__ curn,
                       int* __restrict__ adjp, int* __restrict__ adjn, int E){
  int i = blockIdx.x * 256 + threadIdx.x;
  if (i < E){
    int r = pr[i]; int p = atomicAdd(curp + r, 1); adjp[op[r] + p] = pc[i];
    r = nr[i];     p = atomicAdd(curn + r, 1);     adjn[on[r] + p] = nc[i];
  }
}

// ---------- base layer: mean-gather + self + bias, l2norm, tanh ----------
__device__ inline float gather_mean(const float* __restrict__ XW, const int* __restrict__ adj,
                                    int base, int d, int col){
  float s = 0.f; int j = 0;
  for (; j + 4 <= d; j += 4){
    int n0 = adj[base + j], n1 = adj[base + j + 1], n2 = adj[base + j + 2], n3 = adj[base + j + 3];
    s += XW[(size_t)n0 * 256 + col] + XW[(size_t)n1 * 256 + col]
       + XW[(size_t)n2 * 256 + col] + XW[(size_t)n3 * 256 + col];
  }
  for (; j < d; ++j) s += XW[(size_t)adj[base + j] * 256 + col];
  return s / (float)(d > 0 ? d : 1);
}

__global__ __launch_bounds__(256) void k_base(const float* __restrict__ XW,
    const int* __restrict__ adjp, const int* __restrict__ offp, const int* __restrict__ cntp,
    const int* __restrict__ adjn, const int* __restrict__ offn, const int* __restrict__ cntn,
    const float* __restrict__ bp, const float* __restrict__ bn,
    float* __restrict__ hp, float* __restrict__ hn){
  const int wave = threadIdx.x >> 6, lane = threadIdx.x & 63;
  const int node = blockIdx.x * 4 + wave;
  {
    float s = gather_mean(XW, adjp, offp[node], cntp[node], lane);
    float pre = s + XW[(size_t)node * 256 + 64 + lane] + bp[lane];
    float nrm = sqrtf(wave_sum(pre * pre));
    hp[(size_t)node * 64 + lane] = tanhf(pre / fmaxf(nrm, 1e-12f));
  }
  {
    float s = gather_mean(XW, adjn, offn[node], cntn[node], lane + 128);
    float pre = s + XW[(size_t)node * 256 + 192 + lane] + bn[lane];
    float nrm = sqrtf(wave_sum(pre * pre));
    hn[(size_t)node * 64 + lane] = tanhf(pre / fmaxf(nrm, 1e-12f));
  }
}

// ---------- deep layer (fused aggregates + both 192x64 GEMMs + norms + X_mol) ----------
__global__ __launch_bounds__(256) void k_deep(const float* __restrict__ hp, const float* __restrict__ hn,
    const int* __restrict__ adjp, const int* __restrict__ offp, const int* __restrict__ cntp,
    const int* __restrict__ adjn, const int* __restrict__ offn, const int* __restrict__ cntn,
    const float* __restrict__ Wpd, const float* __restrict__ bpd,
    const float* __restrict__ Wnd, const float* __restrict__ bnd,
    float* __restrict__ xmol, __hip_bfloat16* __restrict__ Xmb){
  const int wave = threadIdx.x >> 6, lane = threadIdx.x & 63;
  const int node = blockIdx.x * 4 + wave;
  const float mhp = hp[(size_t)node * 64 + lane];
  const float mhn = hn[(size_t)node * 64 + lane];
  float a1p = 0.f, a1n = 0.f;
  {
    int d = cntp[node], base = offp[node]; int j = 0;
    for (; j + 2 <= d; j += 2){
      int n0 = adjp[base + j], n1 = adjp[base + j + 1];
      a1p += hp[(size_t)n0 * 64 + lane] + hp[(size_t)n1 * 64 + lane];
      a1n += hn[(size_t)n0 * 64 + lane] + hn[(size_t)n1 * 64 + lane];
    }
    for (; j < d; ++j){ int n0 = adjp[base + j]; a1p += hp[(size_t)n0 * 64 + lane]; a1n += hn[(size_t)n0 * 64 + lane]; }
    float inv = 1.f / (float)(d > 0 ? d : 1); a1p *= inv; a1n *= inv;
  }
  float a2p = 0.f, a2n = 0.f;
  {
    int d = cntn[node], base = offn[node]; int j = 0;
    for (; j + 2 <= d; j += 2){
      int n0 = adjn[base + j], n1 = adjn[base + j + 1];
      a2p += hn[(size_t)n0 * 64 + lane] + hn[(size_t)n1 * 64 + lane];
      a2n += hp[(size_t)n0 * 64 + lane] + hp[(size_t)n1 * 64 + lane];
    }
    for (; j < d; ++j){ int n0 = adjn[base + j]; a2p += hn[(size_t)n0 * 64 + lane]; a2n += hp[(size_t)n0 * 64 + lane]; }
    float inv = 1.f / (float)(d > 0 ? d : 1); a2p *= inv; a2n *= inv;
  }
  float accp = bpd[lane], accn = bnd[lane];
#pragma unroll 4
  for (int k = 0; k < 64; ++k){
    float p1 = __shfl(a1p, k, 64), p2 = __shfl(a2p, k, 64), p3 = __shfl(mhp, k, 64);
    float q1 = __shfl(a1n, k, 64), q2 = __shfl(a2n, k, 64), q3 = __shfl(mhn, k, 64);
    accp += p1 * Wpd[k * 64 + lane] + p2 * Wpd[(64 + k) * 64 + lane] + p3 * Wpd[(128 + k) * 64 + lane];
    accn += q1 * Wnd[k * 64 + lane] + q2 * Wnd[(64 + k) * 64 + lane] + q3 * Wnd[(128 + k) * 64 + lane];
  }
  float np = sqrtf(wave_sum(accp * accp));
  float h2p = tanhf(accp / fmaxf(np, 1e-12f));
  float nn = sqrtf(wave_sum(accn * accn));
  float h2n = tanhf(accn / fmaxf(nn, 1e-12f));
  float nz = sqrtf(wave_sum(h2p * h2p + h2n * h2n));
  float xp = h2p / fmaxf(nz, 1e-12f);
  float xn = h2n / fmaxf(nz, 1e-12f);
  xmol[(size_t)node * 128 + lane] = xp;
  xmol[(size_t)node * 128 + 64 + lane] = xn;
  Xmb[(size_t)node * 128 + lane] = __float2bfloat16(xp);
  Xmb[(size_t)node * 128 + 64 + lane] = __float2bfloat16(xn);
}

// ---------- pred = (Xm @ Xm^T) * mask ; persistent chunk + software pipeline ----------
// Block owns 64 rows x CHUNK cols; loops over NT tiles of 64x128 with a
// 2-stage pipeline: ISSUE(t+1) NT-loads -> MFMA(t) -> LDS transpose ->
// CONSUME(t) (vmcnt wait drains loads issued a full iteration earlier).
// Static double-buffer (mA/lA, mB/lB; loop unrolled x2 -> no runtime index).
// LDS tile is wave-local; per-wave in-order DS makes the reuse safe, no barriers.
__global__ __launch_bounds__(256, 2) void k_pred(const __hip_bfloat16* __restrict__ Xmb,
    const float* __restrict__ mask, const float* __restrict__ labels,
    float* __restrict__ pred, float* __restrict__ partial, int N){
  const int wave = threadIdx.x >> 6, lane = threadIdx.x & 63;
  const int ti = blockIdx.y * 64 + wave * 16;
  const int cbase = blockIdx.x * CHUNK;
  const int r0 = lane & 15, kq = (lane >> 4) * 8;
  const unsigned short* X = (const unsigned short*)Xmb;

  // loop-invariant A fragments
  bf16x8 a[4];
#pragma unroll
  for (int ks = 0; ks < 4; ++ks)
    a[ks] = *(const bf16x8*)(X + (size_t)(ti + r0) * 128 + ks * 32 + kq);

  __shared__ float tile[4][16][132];   // pad 132: 528B rows, 16B-aligned
  __shared__ float wsum[4];
  const int hi = lane >> 5, c = lane & 31;
  const int rb = (lane >> 4) * 4, c16 = lane & 15;

  float lsum = 0.f;
  f32x4 mA[8], lA[8], mB[8], lB[8];

  auto ISSUE = [&](f32x4* mm, f32x4* ll, int t){
    int tj = cbase + t * 128;
#pragma unroll
    for (int g = 0; g < 8; ++g){
      size_t idx = (size_t)(ti + g * 2 + hi) * N + tj + c * 4;
      mm[g] = __builtin_nontemporal_load((const f32x4*)(mask + idx));
      ll[g] = __builtin_nontemporal_load((const f32x4*)(labels + idx));
    }
    __builtin_amdgcn_sched_barrier(0);   // pin loads here; no sinking
  };
  auto MFMA_T = [&](int t){
    int tj = cbase + t * 128;
    f32x4 acc[2][4] = {};
#pragma unroll
    for (int ks = 0; ks < 4; ++ks){
      int kb = ks * 32 + kq;
#pragma unroll
      for (int pan = 0; pan < 2; ++pan)
#pragma unroll
        for (int js = 0; js < 4; ++js){
          bf16x8 b = *(const bf16x8*)(X + (size_t)(tj + pan * 64 + js * 16 + r0) * 128 + kb);
          acc[pan][js] = __builtin_amdgcn_mfma_f32_16x16x32_bf16(a[ks], b, acc[pan][js], 0, 0, 0);
        }
    }
#pragma unroll
    for (int pan = 0; pan < 2; ++pan)
#pragma unroll
      for (int js = 0; js < 4; ++js)
#pragma unroll
        for (int i = 0; i < 4; ++i)
          tile[wave][rb + i][pan * 64 + js * 16 + c16] = acc[pan][js][i];
  };
  auto CONSUME = [&](const f32x4* mm, const f32x4* ll, int t){
    int tj = cbase + t * 128;
#pragma unroll
    for (int g = 0; g < 8; ++g){
      int row = g * 2 + hi;
      f32x4 av = *(const f32x4*)&tile[wave][row][c * 4];
      f32x4 pv = av * mm[g];
      f32x4 d = pv - ll[g];
      lsum += d[0]*d[0] + d[1]*d[1] + d[2]*d[2] + d[3]*d[3];
      size_t idx = (size_t)(ti + row) * N + tj + c * 4;
      // pred base is at odd float offset in d_out -> scalar NT stores
      __builtin_nontemporal_store(pv[0], pred + idx);
      __builtin_nontemporal_store(pv[1], pred + idx + 1);
      __builtin_nontemporal_store(pv[2], pred + idx + 2);
      __builtin_nontemporal_store(pv[3], pred + idx + 3);
    }
  };

  ISSUE(mA, lA, 0);
#pragma unroll 1
  for (int t = 0; t < NT; t += 2){
    MFMA_T(t);
    ISSUE(mB, lB, t + 1);
    CONSUME(mA, lA, t);
    MFMA_T(t + 1);
    if (t + 2 < NT) ISSUE(mA, lA, t + 2);
    CONSUME(mB, lB, t + 1);
  }

  lsum = wave_sum(lsum);
  if (lane == 0) wsum[wave] = lsum;
  __syncthreads();
  if (threadIdx.x == 0)
    partial[blockIdx.y * gridDim.x + blockIdx.x] = wsum[0] + wsum[1] + wsum[2] + wsum[3];
}

__global__ __launch_bounds__(1024) void k_loss_fin(const float* __restrict__ partial,
                                                   float* __restrict__ out, float inv, int n){
  float s = 0.f;
  for (int i = threadIdx.x; i < n; i += 1024) s += partial[i];
  s = wave_sum(s);
  __shared__ float ws[16];
  if ((threadIdx.x & 63) == 0) ws[threadIdx.x >> 6] = s;
  __syncthreads();
  if (threadIdx.x == 0){
    float t = 0.f;
#pragma unroll
    for (int w = 0; w < 16; ++w) t += ws[w];
    out[0] = t * inv;
  }
}

extern "C" void kernel_launch(void* const* d_in, const int* in_sizes, int n_in,
                              void* d_out, int out_size, void* d_ws, size_t ws_size,
                              hipStream_t stream){
  const float* X      = (const float*)d_in[0];
  const int*   pe     = (const int*)d_in[1];
  const int*   ne     = (const int*)d_in[2];
  const float* labels = (const float*)d_in[3];
  const float* mask   = (const float*)d_in[4];
  const float* Wpb    = (const float*)d_in[5];
  const float* bpb    = (const float*)d_in[6];
  const float* Wnb    = (const float*)d_in[7];
  const float* bnb    = (const float*)d_in[8];
  const float* Wpd    = (const float*)d_in[9];
  const float* bpd    = (const float*)d_in[10];
  const float* Wnd    = (const float*)d_in[11];
  const float* bnd    = (const float*)d_in[12];
  const int N = in_sizes[0] / DIN;       // 8192
  const int E = in_sizes[1] / 2;         // 262144

  char* ws = (char*)d_ws;
  size_t off = 0;
  auto alloc = [&](size_t bytes){ void* p = ws + off; off = (off + bytes + 255) & ~(size_t)255; return p; };
  float* XW            = (float*)alloc((size_t)N * 256 * 4);
  float* hp            = (float*)alloc((size_t)N * 64 * 4);
  float* hn            = (float*)alloc((size_t)N * 64 * 4);
  __hip_bfloat16* Xmb  = (__hip_bfloat16*)alloc((size_t)N * 128 * 2);
  __hip_bfloat16* Xb   = (__hip_bfloat16*)alloc((size_t)N * KP * 2);
  __hip_bfloat16* Wtb  = (__hip_bfloat16*)alloc((size_t)256 * KP * 2);
  int* adjp            = (int*)alloc((size_t)E * 4);
  int* adjn            = (int*)alloc((size_t)E * 4);
  char* zbase = ws + off;                 // zeroed region start
  int* cntp            = (int*)alloc((size_t)N * 4);
  int* cntn            = (int*)alloc((size_t)N * 4);
  int* curp            = (int*)alloc((size_t)N * 4);
  int* curn            = (int*)alloc((size_t)N * 4);
  size_t zbytes = (size_t)((ws + off) - zbase);
  int* offp            = (int*)alloc((size_t)N * 4);
  int* offn            = (int*)alloc((size_t)N * 4);
  float* partial       = (float*)alloc((size_t)(N / 64) * (N / CHUNK) * 4);
  (void)ws_size; (void)n_in; (void)out_size;

  float* out_loss = (float*)d_out;
  float* out_xmol = out_loss + 1;
  float* out_pred = out_xmol + (size_t)N * 128;

  hipMemsetAsync(zbase, 0, zbytes, stream);
  k_cvtX<<<N, 256, 0, stream>>>(X, Xb);
  k_cvtW<<<256, 256, 0, stream>>>(Wpb, Wnb, Wtb);
  k_gemm_base<<<dim3(4, N / 64), 256, 0, stream>>>(Xb, Wtb, XW);
  k_hist<<<(E + 255) / 256, 256, 0, stream>>>(pe, ne, cntp, cntn, E);
  k_scan<<<2, 1024, 0, stream>>>(cntp, offp, cntn, offn, N);
  k_fill<<<(E + 255) / 256, 256, 0, stream>>>(pe, pe + E, ne, ne + E, offp, offn, curp, curn, adjp, adjn, E);
  k_base<<<N / 4, 256, 0, stream>>>(XW, adjp, offp, cntp, adjn, offn, cntn, bpb, bnb, hp, hn);
  k_deep<<<N / 4, 256, 0, stream>>>(hp, hn, adjp, offp, cntp, adjn, offn, cntn,
                                    Wpd, bpd, Wnd, bnd, out_xmol, Xmb);
  k_pred<<<dim3(N / CHUNK, N / 64), 256, 0, stream>>>(Xmb, mask, labels, out_pred, partial, N);
  k_loss_fin<<<1, 1024, 0, stream>>>(partial, out_loss, 1.0f / ((float)N * (float)N), (N / 64) * (N / CHUNK));
}

// Round 6
// 354.483 us; speedup vs baseline: 1.1918x; 1.1918x over previous
//
#include <hip/hip_runtime.h>
#include <hip/hip_bf16.h>

#define DIN 300
#define KP  320            // K padded to multiple of 32 for MFMA
#define NH  64

typedef __bf16 bf16x8 __attribute__((ext_vector_type(8)));
typedef float  f32x4  __attribute__((ext_vector_type(4)));

__device__ inline float wave_sum(float v){
#pragma unroll
  for (int m = 32; m >= 1; m >>= 1) v += __shfl_xor(v, m, 64);
  return v;
}

// ---------- convert X -> bf16 padded [N][KP] ----------
__global__ __launch_bounds__(256) void k_cvtX(const float* __restrict__ X,
                                              __hip_bfloat16* __restrict__ Xb){
  int row = blockIdx.x;
  const float* xr = X + (size_t)row * DIN;
  __hip_bfloat16* o = Xb + (size_t)row * KP;
  for (int k = threadIdx.x; k < KP; k += 256)
    o[k] = __float2bfloat16(k < DIN ? xr[k] : 0.f);
}

// ---------- build transposed weight [256][KP] bf16: cols = [Wt_pos|Wb_pos|Wt_neg|Wb_neg] ----------
__global__ __launch_bounds__(256) void k_cvtW(const float* __restrict__ Wpb,
                                              const float* __restrict__ Wnb,
                                              __hip_bfloat16* __restrict__ Wtb){
  int c = blockIdx.x;                 // 0..255
  int sel = c >> 6, jj = c & 63;
  const float* W = (sel < 2 ? Wpb : Wnb) + (size_t)(sel & 1) * DIN * NH + jj;
  __hip_bfloat16* o = Wtb + (size_t)c * KP;
  for (int k = threadIdx.x; k < KP; k += 256)
    o[k] = __float2bfloat16(k < DIN ? W[(size_t)k * NH] : 0.f);
}

// ---------- XW[N][256] = Xb @ Wcat  (MFMA bf16) ----------
__global__ __launch_bounds__(256) void k_gemm_base(const __hip_bfloat16* __restrict__ Xb,
                                                   const __hip_bfloat16* __restrict__ Wtb,
                                                   float* __restrict__ XW){
  const int wave = threadIdx.x >> 6, lane = threadIdx.x & 63;
  const int ti = blockIdx.y * 64 + wave * 16;     // row tile (16 rows/wave)
  const int cj = blockIdx.x * 64;                 // col tile
  const int r0 = lane & 15, kq = (lane >> 4) * 8;
  const unsigned short* Xp = (const unsigned short*)Xb;
  const unsigned short* Wp = (const unsigned short*)Wtb;
  f32x4 acc[4] = {};
  for (int ks = 0; ks < KP / 32; ++ks){
    int kb = ks * 32 + kq;
    bf16x8 a = *(const bf16x8*)(Xp + (size_t)(ti + r0) * KP + kb);
#pragma unroll
    for (int js = 0; js < 4; ++js){
      bf16x8 b = *(const bf16x8*)(Wp + (size_t)(cj + js * 16 + r0) * KP + kb);
      acc[js] = __builtin_amdgcn_mfma_f32_16x16x32_bf16(a, b, acc[js], 0, 0, 0);
    }
  }
  const int orow = ti + (lane >> 4) * 4;
  const int oc = cj + (lane & 15);
#pragma unroll
  for (int js = 0; js < 4; ++js)
#pragma unroll
    for (int i = 0; i < 4; ++i)
      XW[(size_t)(orow + i) * 256 + oc + js * 16] = acc[js][i];
}

// ---------- CSR build ----------
__global__ void k_hist(const int* __restrict__ pr, const int* __restrict__ nr,
                       int* __restrict__ cp, int* __restrict__ cn, int E){
  int i = blockIdx.x * 256 + threadIdx.x;
  if (i < E){ atomicAdd(cp + pr[i], 1); atomicAdd(cn + nr[i], 1); }
}

__global__ __launch_bounds__(1024) void k_scan(const int* __restrict__ c0, int* __restrict__ o0,
                                               const int* __restrict__ c1, int* __restrict__ o1, int n){
  const int* cnt = blockIdx.x ? c1 : c0;
  int* off = blockIdx.x ? o1 : o0;
  __shared__ int lds[1024];
  int t = threadIdx.x;
  int ept = n >> 10;
  int s = 0;
  for (int i = 0; i < ept; ++i) s += cnt[t * ept + i];
  lds[t] = s; __syncthreads();
  for (int d = 1; d < 1024; d <<= 1){
    int add = (t >= d) ? lds[t - d] : 0;
    __syncthreads();
    lds[t] += add;
    __syncthreads();
  }
  int base = t ? lds[t - 1] : 0;
  for (int i = 0; i < ept; ++i){ off[t * ept + i] = base; base += cnt[t * ept + i]; }
}

__global__ void k_fill(const int* __restrict__ pr, const int* __restrict__ pc,
                       const int* __restrict__ nr, const int* __restrict__ nc,
                       const int* __restrict__ op, const int* __restrict__ on,
                       int* __restrict__ curp, int* __restrict__ curn,
                       int* __restrict__ adjp, int* __restrict__ adjn, int E){
  int i = blockIdx.x * 256 + threadIdx.x;
  if (i < E){
    int r = pr[i]; int p = atomicAdd(curp + r, 1); adjp[op[r] + p] = pc[i];
    r = nr[i];     p = atomicAdd(curn + r, 1);     adjn[on[r] + p] = nc[i];
  }
}

// ---------- base layer: mean-gather + self + bias, l2norm, tanh ----------
__device__ inline float gather_mean(const float* __restrict__ XW, const int* __restrict__ adj,
                                    int base, int d, int col){
  float s = 0.f; int j = 0;
  for (; j + 4 <= d; j += 4){
    int n0 = adj[base + j], n1 = adj[base + j + 1], n2 = adj[base + j + 2], n3 = adj[base + j + 3];
    s += XW[(size_t)n0 * 256 + col] + XW[(size_t)n1 * 256 + col]
       + XW[(size_t)n2 * 256 + col] + XW[(size_t)n3 * 256 + col];
  }
  for (; j < d; ++j) s += XW[(size_t)adj[base + j] * 256 + col];
  return s / (float)(d > 0 ? d : 1);
}

__global__ __launch_bounds__(256) void k_base(const float* __restrict__ XW,
    const int* __restrict__ adjp, const int* __restrict__ offp, const int* __restrict__ cntp,
    const int* __restrict__ adjn, const int* __restrict__ offn, const int* __restrict__ cntn,
    const float* __restrict__ bp, const float* __restrict__ bn,
    float* __restrict__ hp, float* __restrict__ hn){
  const int wave = threadIdx.x >> 6, lane = threadIdx.x & 63;
  const int node = blockIdx.x * 4 + wave;
  {
    float s = gather_mean(XW, adjp, offp[node], cntp[node], lane);
    float pre = s + XW[(size_t)node * 256 + 64 + lane] + bp[lane];
    float nrm = sqrtf(wave_sum(pre * pre));
    hp[(size_t)node * 64 + lane] = tanhf(pre / fmaxf(nrm, 1e-12f));
  }
  {
    float s = gather_mean(XW, adjn, offn[node], cntn[node], lane + 128);
    float pre = s + XW[(size_t)node * 256 + 192 + lane] + bn[lane];
    float nrm = sqrtf(wave_sum(pre * pre));
    hn[(size_t)node * 64 + lane] = tanhf(pre / fmaxf(nrm, 1e-12f));
  }
}

// ---------- deep layer (fused aggregates + both 192x64 GEMMs + norms + X_mol) ----------
__global__ __launch_bounds__(256) void k_deep(const float* __restrict__ hp, const float* __restrict__ hn,
    const int* __restrict__ adjp, const int* __restrict__ offp, const int* __restrict__ cntp,
    const int* __restrict__ adjn, const int* __restrict__ offn, const int* __restrict__ cntn,
    const float* __restrict__ Wpd, const float* __restrict__ bpd,
    const float* __restrict__ Wnd, const float* __restrict__ bnd,
    float* __restrict__ xmol, __hip_bfloat16* __restrict__ Xmb){
  const int wave = threadIdx.x >> 6, lane = threadIdx.x & 63;
  const int node = blockIdx.x * 4 + wave;
  const float mhp = hp[(size_t)node * 64 + lane];
  const float mhn = hn[(size_t)node * 64 + lane];
  float a1p = 0.f, a1n = 0.f;
  {
    int d = cntp[node], base = offp[node]; int j = 0;
    for (; j + 2 <= d; j += 2){
      int n0 = adjp[base + j], n1 = adjp[base + j + 1];
      a1p += hp[(size_t)n0 * 64 + lane] + hp[(size_t)n1 * 64 + lane];
      a1n += hn[(size_t)n0 * 64 + lane] + hn[(size_t)n1 * 64 + lane];
    }
    for (; j < d; ++j){ int n0 = adjp[base + j]; a1p += hp[(size_t)n0 * 64 + lane]; a1n += hn[(size_t)n0 * 64 + lane]; }
    float inv = 1.f / (float)(d > 0 ? d : 1); a1p *= inv; a1n *= inv;
  }
  float a2p = 0.f, a2n = 0.f;
  {
    int d = cntn[node], base = offn[node]; int j = 0;
    for (; j + 2 <= d; j += 2){
      int n0 = adjn[base + j], n1 = adjn[base + j + 1];
      a2p += hn[(size_t)n0 * 64 + lane] + hn[(size_t)n1 * 64 + lane];
      a2n += hp[(size_t)n0 * 64 + lane] + hp[(size_t)n1 * 64 + lane];
    }
    for (; j < d; ++j){ int n0 = adjn[base + j]; a2p += hn[(size_t)n0 * 64 + lane]; a2n += hp[(size_t)n0 * 64 + lane]; }
    float inv = 1.f / (float)(d > 0 ? d : 1); a2p *= inv; a2n *= inv;
  }
  float accp = bpd[lane], accn = bnd[lane];
#pragma unroll 4
  for (int k = 0; k < 64; ++k){
    float p1 = __shfl(a1p, k, 64), p2 = __shfl(a2p, k, 64), p3 = __shfl(mhp, k, 64);
    float q1 = __shfl(a1n, k, 64), q2 = __shfl(a2n, k, 64), q3 = __shfl(mhn, k, 64);
    accp += p1 * Wpd[k * 64 + lane] + p2 * Wpd[(64 + k) * 64 + lane] + p3 * Wpd[(128 + k) * 64 + lane];
    accn += q1 * Wnd[k * 64 + lane] + q2 * Wnd[(64 + k) * 64 + lane] + q3 * Wnd[(128 + k) * 64 + lane];
  }
  float np = sqrtf(wave_sum(accp * accp));
  float h2p = tanhf(accp / fmaxf(np, 1e-12f));
  float nn = sqrtf(wave_sum(accn * accn));
  float h2n = tanhf(accn / fmaxf(nn, 1e-12f));
  float nz = sqrtf(wave_sum(h2p * h2p + h2n * h2n));
  float xp = h2p / fmaxf(nz, 1e-12f);
  float xn = h2n / fmaxf(nz, 1e-12f);
  xmol[(size_t)node * 128 + lane] = xp;
  xmol[(size_t)node * 128 + 64 + lane] = xn;
  Xmb[(size_t)node * 128 + lane] = __float2bfloat16(xp);
  Xmb[(size_t)node * 128 + 64 + lane] = __float2bfloat16(xn);
}

// ---------- pred = (Xm @ Xm^T) * mask ; per-block loss partials ----------
// Block tile 64x128 (wave: 16x128). launch_bounds(256,2) gives the register
// allocator a 256-VGPR budget so the ENTIRE 32-load burst (16 mask + 16 label
// f32x4 = 128 VGPRs payload) stays in named registers -> 16KB/wave in flight.
// ISSUE placed right after MFMA so load latency overlaps the LDS transpose.
__global__ __launch_bounds__(256, 2) void k_pred(const __hip_bfloat16* __restrict__ Xmb,
    const float* __restrict__ mask, const float* __restrict__ labels,
    float* __restrict__ pred, float* __restrict__ partial, int N){
  const int wave = threadIdx.x >> 6, lane = threadIdx.x & 63;
  const int ti = blockIdx.y * 64 + wave * 16;
  const int tj = blockIdx.x * 128;
  const int r0 = lane & 15, kq = (lane >> 4) * 8;
  const unsigned short* X = (const unsigned short*)Xmb;
  f32x4 acc[2][4] = {};
#pragma unroll
  for (int ks = 0; ks < 4; ++ks){
    int kb = ks * 32 + kq;
    bf16x8 a = *(const bf16x8*)(X + (size_t)(ti + r0) * 128 + kb);
#pragma unroll
    for (int pan = 0; pan < 2; ++pan)
#pragma unroll
      for (int js = 0; js < 4; ++js){
        bf16x8 b = *(const bf16x8*)(X + (size_t)(tj + pan * 64 + js * 16 + r0) * 128 + kb);
        acc[pan][js] = __builtin_amdgcn_mfma_f32_16x16x32_bf16(a, b, acc[pan][js], 0, 0, 0);
      }
  }
  // issue the full mask/label burst NOW (doesn't depend on acc); latency
  // overlaps the LDS transpose below
  const int hi = lane >> 5, c = lane & 31;
  f32x4 m[8], lb[8];
#pragma unroll
  for (int g = 0; g < 8; ++g){
    size_t idx = (size_t)(ti + g * 2 + hi) * N + tj + c * 4;
    m[g]  = __builtin_nontemporal_load((const f32x4*)(mask + idx));
    lb[g] = __builtin_nontemporal_load((const f32x4*)(labels + idx));
  }
  // transpose 16x128 wave tile through LDS; pad 132 (528B rows, 16B-aligned)
  __shared__ float tile[4][16][132];
  __shared__ float wsum[4];
  const int rb = (lane >> 4) * 4, c16 = lane & 15;
#pragma unroll
  for (int pan = 0; pan < 2; ++pan)
#pragma unroll
    for (int js = 0; js < 4; ++js)
#pragma unroll
      for (int i = 0; i < 4; ++i)
        tile[wave][rb + i][pan * 64 + js * 16 + c16] = acc[pan][js][i];
  float lsum = 0.f;
#pragma unroll
  for (int g = 0; g < 8; ++g){
    int row = g * 2 + hi;
    f32x4 a = *(const f32x4*)&tile[wave][row][c * 4];
    f32x4 pv = a * m[g];
    f32x4 d = pv - lb[g];
    lsum += d[0]*d[0] + d[1]*d[1] + d[2]*d[2] + d[3]*d[3];
    size_t idx = (size_t)(ti + row) * N + tj + c * 4;
    // pred base is at odd float offset in d_out -> scalar NT stores
    __builtin_nontemporal_store(pv[0], pred + idx);
    __builtin_nontemporal_store(pv[1], pred + idx + 1);
    __builtin_nontemporal_store(pv[2], pred + idx + 2);
    __builtin_nontemporal_store(pv[3], pred + idx + 3);
  }
  lsum = wave_sum(lsum);
  if (lane == 0) wsum[wave] = lsum;
  __syncthreads();
  if (threadIdx.x == 0)
    partial[blockIdx.y * gridDim.x + blockIdx.x] = wsum[0] + wsum[1] + wsum[2] + wsum[3];
}

__global__ __launch_bounds__(1024) void k_loss_fin(const float* __restrict__ partial,
                                                   float* __restrict__ out, float inv, int n){
  float s = 0.f;
  for (int i = threadIdx.x; i < n; i += 1024) s += partial[i];
  s = wave_sum(s);
  __shared__ float ws[16];
  if ((threadIdx.x & 63) == 0) ws[threadIdx.x >> 6] = s;
  __syncthreads();
  if (threadIdx.x == 0){
    float t = 0.f;
#pragma unroll
    for (int w = 0; w < 16; ++w) t += ws[w];
    out[0] = t * inv;
  }
}

extern "C" void kernel_launch(void* const* d_in, const int* in_sizes, int n_in,
                              void* d_out, int out_size, void* d_ws, size_t ws_size,
                              hipStream_t stream){
  const float* X      = (const float*)d_in[0];
  const int*   pe     = (const int*)d_in[1];
  const int*   ne     = (const int*)d_in[2];
  const float* labels = (const float*)d_in[3];
  const float* mask   = (const float*)d_in[4];
  const float* Wpb    = (const float*)d_in[5];
  const float* bpb    = (const float*)d_in[6];
  const float* Wnb    = (const float*)d_in[7];
  const float* bnb    = (const float*)d_in[8];
  const float* Wpd    = (const float*)d_in[9];
  const float* bpd    = (const float*)d_in[10];
  const float* Wnd    = (const float*)d_in[11];
  const float* bnd    = (const float*)d_in[12];
  const int N = in_sizes[0] / DIN;       // 8192
  const int E = in_sizes[1] / 2;         // 262144

  char* ws = (char*)d_ws;
  size_t off = 0;
  auto alloc = [&](size_t bytes){ void* p = ws + off; off = (off + bytes + 255) & ~(size_t)255; return p; };
  float* XW            = (float*)alloc((size_t)N * 256 * 4);
  float* hp            = (float*)alloc((size_t)N * 64 * 4);
  float* hn            = (float*)alloc((size_t)N * 64 * 4);
  __hip_bfloat16* Xmb  = (__hip_bfloat16*)alloc((size_t)N * 128 * 2);
  __hip_bfloat16* Xb   = (__hip_bfloat16*)alloc((size_t)N * KP * 2);
  __hip_bfloat16* Wtb  = (__hip_bfloat16*)alloc((size_t)256 * KP * 2);
  int* adjp            = (int*)alloc((size_t)E * 4);
  int* adjn            = (int*)alloc((size_t)E * 4);
  char* zbase = ws + off;                 // zeroed region start
  int* cntp            = (int*)alloc((size_t)N * 4);
  int* cntn            = (int*)alloc((size_t)N * 4);
  int* curp            = (int*)alloc((size_t)N * 4);
  int* curn            = (int*)alloc((size_t)N * 4);
  size_t zbytes = (size_t)((ws + off) - zbase);
  int* offp            = (int*)alloc((size_t)N * 4);
  int* offn            = (int*)alloc((size_t)N * 4);
  float* partial       = (float*)alloc((size_t)(N / 64) * (N / 128) * 4);
  (void)ws_size; (void)n_in; (void)out_size;

  float* out_loss = (float*)d_out;
  float* out_xmol = out_loss + 1;
  float* out_pred = out_xmol + (size_t)N * 128;

  hipMemsetAsync(zbase, 0, zbytes, stream);
  k_cvtX<<<N, 256, 0, stream>>>(X, Xb);
  k_cvtW<<<256, 256, 0, stream>>>(Wpb, Wnb, Wtb);
  k_gemm_base<<<dim3(4, N / 64), 256, 0, stream>>>(Xb, Wtb, XW);
  k_hist<<<(E + 255) / 256, 256, 0, stream>>>(pe, ne, cntp, cntn, E);
  k_scan<<<2, 1024, 0, stream>>>(cntp, offp, cntn, offn, N);
  k_fill<<<(E + 255) / 256, 256, 0, stream>>>(pe, pe + E, ne, ne + E, offp, offn, curp, curn, adjp, adjn, E);
  k_base<<<N / 4, 256, 0, stream>>>(XW, adjp, offp, cntp, adjn, offn, cntn, bpb, bnb, hp, hn);
  k_deep<<<N / 4, 256, 0, stream>>>(hp, hn, adjp, offp, cntp, adjn, offn, cntn,
                                    Wpd, bpd, Wnd, bnd, out_xmol, Xmb);
  k_pred<<<dim3(N / 128, N / 64), 256, 0, stream>>>(Xmb, mask, labels, out_pred, partial, N);
  k_loss_fin<<<1, 1024, 0, stream>>>(partial, out_loss, 1.0f / ((float)N * (float)N), (N / 64) * (N / 128));
}